// Round 5
// baseline (5194.118 us; speedup 1.0000x reference)
//
#include <hip/hip_runtime.h>

// Delayed-feedback LSTM, persistent kernel: 256 WGs (1/CU), 512 threads.
// LAW (r0-r4, five configs): the toolchain caps ARCH VGPRs at 128/thread for
// 512-thr WGs (64 for 1024-thr) regardless of launch_bounds / waves_per_eu /
// flat_work_group_size / static-LDS occupancy. Overcommitting spills to
// scratch whose per-XCD footprint (8 MB) exceeds L2 -> HBM-latency-bound
// reloads (r4: FETCH 2.26 GB, 5.03 ms).
// THIS ROUND: claim the OTHER half of the gfx950 unified register file —
// AGPRs — via explicit v_accvgpr_write/read inline asm ("a" constraints),
// which the scheduler can neither remat nor sink. W_hh split per gate
// (32 f16 pairs):
//   pairs  0..9  -> VGPRs   wregv[8][10] = 80 regs (+~45 working <= 128 cap)
//   pairs 10..16 -> LDS     114.7 KB (uint4+uint2+u32, b128/b64/b32 reads)
//   pairs 17..31 -> AGPRs   wag[8][15] = 120 AGPRs (240 KB chip-wide)
// => W_hh fully on-chip, ZERO per-step global traffic. AGPR use costs one
// v_accvgpr_read per pair per step (~120 VALU/thread/step, ~0.13 ms total).
// Serial h-matvec: kq=tid>>7 (k-quarter), gl=tid&127 (8 gates/thread);
// h reads are wave-uniform LDS broadcasts. Chunk phase (CH=8) unchanged.

#define BATCH   256
#define TSTEPS  1024
#define IN_DIM  64
#define HID     256
#define OUT_DIM 64
#define DELAY   20
#define CH      8
#define NCH     (TSTEPS / CH)
#define NTHR    512
#define REGV    10              // f16 pairs per gate in arch VGPRs
#define AGP     15              // f16 pairs per gate in AGPRs

typedef unsigned int u32;
typedef _Float16 half2_t __attribute__((ext_vector_type(2)));

union H2U { u32 u; half2_t h; };
union H1U { unsigned short s; _Float16 h; };

__device__ __forceinline__ u32 pack2(float a, float b) {
    H2U x; x.h = half2_t{(_Float16)a, (_Float16)b}; return x.u;
}
__device__ __forceinline__ unsigned short f16bits(float a) {
    H1U x; x.h = (_Float16)a; return x.s;
}
__device__ __forceinline__ float lo16(u32 u) {
    H1U x; x.s = (unsigned short)(u & 0xffffu); return (float)x.h;
}
__device__ __forceinline__ float hi16(u32 u) {
    H1U x; x.s = (unsigned short)(u >> 16); return (float)x.h;
}
__device__ __forceinline__ float dot2(u32 w, u32 h, float acc) {
    H2U a; a.u = w; H2U b; b.u = h;
    return __builtin_amdgcn_fdot2(a.h, b.h, acc, false);
}
__device__ __forceinline__ float sigm(float x) {
    float e = __expf(-fabsf(x));
    float p = 1.f / (1.f + e);
    return x >= 0.f ? p : 1.f - p;
}
__device__ __forceinline__ float tanh_f(float x) {
    float e = __expf(-2.f * fabsf(x));
    float r = (1.f - e) / (1.f + e);
    return x >= 0.f ? r : -r;
}

// AGPR access macros (gfx90a+/gfx950 unified file)
#define AGWRITE(dst, src) \
    asm volatile("v_accvgpr_write_b32 %0, %1" : "=a"(dst) : "v"(src))
#define AGREAD(dst, src) \
    asm volatile("v_accvgpr_read_b32 %0, %1" : "=v"(dst) : "a"(src))

// STATIC LDS layout (bytes), total 152192 <= 163840
#define OFF_WA    0        // uint4[8 q][512 tid]   65536  W_hh pairs 10..13
#define OFF_WB    65536    // uint2[8 q][512 tid]   32768  W_hh pairs 14..15
#define OFF_WC    98304    // u32  [8 q][512 tid]   16384  W_hh pair 16
#define OFF_CB    114688   // u32  [8 tl][512]      16384  chunk pre-acts (2 gates/u32)
#define OFF_PART  131072   // ushort[4 kq][1024 g]   8192  per-kq partials (f16)
#define OFF_RING  139264   // ushort[20][64]         2560  fb ring (f16)
#define OFF_XF    141824   // u32[8][68]             2176  staged x|fb pairs
#define OFF_HG    144000   // ushort[16][256]        8192  h history (f16)
#define SMEM_BYTES 152192

// ws layout (bytes)
#define WS_BPK   0         // 262144: chunk Wx|Wfb packed (uint4)
#define WS_WOUT  262144    // 32768 : packed Wout (u32)
#define WS_BSUM  294912    // 4096  : bias sums (float, permuted)
#define WS_NEED  299008

// permuted gate g' = u*4 + ty  ->  original row ty*256 + u  (ty: 0=i,1=f,2=g,3=o)
__device__ __forceinline__ int orig_row(int gp) {
    return (gp & 3) * 256 + (gp >> 2);
}

__global__ void prepack(const float* __restrict__ Wx,
                        const float* __restrict__ Wfb,
                        const float* __restrict__ Whh,
                        const float* __restrict__ Wout,
                        const float* __restrict__ bih,
                        const float* __restrict__ bhh,
                        uint4* __restrict__ Bpk4,
                        u32* __restrict__ Woutpk,
                        float* __restrict__ bsum_g)
{
    (void)Whh;
    int id = blockIdx.x * 256 + threadIdx.x;
    if (id < 16384) {
        // Bpk4[(j*16+kb)*512 + t]: gate g'=2t+j, K=128 (x|fb), k = kb*8..kb*8+7
        int t = id & 511, rest = id >> 9;
        int kb = rest & 15, j = rest >> 4;
        int r = orig_row(2 * t + j);
        int k0 = kb * 8;
        const float* src = (k0 < 64) ? (Wx + (size_t)r * 64 + k0)
                                     : (Wfb + (size_t)r * 64 + (k0 - 64));
        uint4 v;
        v.x = pack2(src[0], src[1]); v.y = pack2(src[2], src[3]);
        v.z = pack2(src[4], src[5]); v.w = pack2(src[6], src[7]);
        Bpk4[id] = v;
    } else if (id < 16384 + 8192) {
        int s = id - 16384;                 // (w4*64+o)*4+c
        int c = s & 3, o = (s >> 2) & 63, w4 = s >> 8;
        int kp = w4 * 4 + c;
        Woutpk[s] = pack2(Wout[o * HID + 2 * kp], Wout[o * HID + 2 * kp + 1]);
    } else if (id < 16384 + 8192 + 1024) {
        int g = id - 24576;
        int r = orig_row(g);
        bsum_g[g] = bih[r] + bhh[r];
    }
}

__global__ __attribute__((amdgpu_flat_work_group_size(NTHR, NTHR)))
__attribute__((amdgpu_waves_per_eu(2, 2)))
void lstm_persist(const float* __restrict__ input,
                  const float* __restrict__ Whh,
                  const float* __restrict__ bout_g,
                  const uint4* __restrict__ Bpk4,
                  const u32* __restrict__ Woutpk,
                  const float* __restrict__ bsum_g,
                  float* __restrict__ out)
{
    __shared__ alignas(16) unsigned char smem[SMEM_BYTES];
    uint4*          wAl   = (uint4*)(smem + OFF_WA);
    uint2*          wBl   = (uint2*)(smem + OFF_WB);
    u32*            wCl   = (u32*)(smem + OFF_WC);
    u32*            cb32  = (u32*)(smem + OFF_CB);
    unsigned short* part  = (unsigned short*)(smem + OFF_PART);
    unsigned short* ring  = (unsigned short*)(smem + OFF_RING);
    u32*            xfst  = (u32*)(smem + OFF_XF);
    unsigned short* hgs   = (unsigned short*)(smem + OFF_HG);

    const int tid = threadIdx.x;
    const int b   = blockIdx.x;
    const int kq  = tid >> 7;         // wave-uniform k-quarter (32 pairs)
    const int gl  = tid & 127;        // gate block: permuted gates gl*8..gl*8+7

    const float* xin  = input + (size_t)b * TSTEPS * IN_DIM;
    float*       outp = out + (size_t)b * TSTEPS * OUT_DIM;
    const float bo_reg = bout_g[tid & 63];

    // ---- init: W_hh pairs 0..9 -> VGPRs, 10..16 -> LDS, 17..31 -> AGPRs ----
    u32 wregv[8][REGV];
    u32 wag[8][AGP];
#pragma unroll
    for (int q = 0; q < 8; ++q) {
        const int r = orig_row(gl * 8 + q);
        const float* wrow = Whh + (size_t)r * HID + kq * 64;
#pragma unroll
        for (int p = 0; p < REGV; ++p) {
            float2 w2 = *(const float2*)(wrow + 2 * p);
            wregv[q][p] = pack2(w2.x, w2.y);
        }
        uint4 av;
        av.x = pack2(wrow[20], wrow[21]); av.y = pack2(wrow[22], wrow[23]);
        av.z = pack2(wrow[24], wrow[25]); av.w = pack2(wrow[26], wrow[27]);
        wAl[q * 512 + tid] = av;
        uint2 bv;
        bv.x = pack2(wrow[28], wrow[29]); bv.y = pack2(wrow[30], wrow[31]);
        wBl[q * 512 + tid] = bv;
        wCl[q * 512 + tid] = pack2(wrow[32], wrow[33]);
#pragma unroll
        for (int j = 0; j < AGP; ++j) {
            float2 w2 = *(const float2*)(wrow + 34 + 2 * j);
            u32 v = pack2(w2.x, w2.y);
            AGWRITE(wag[q][j], v);
        }
    }
    // zero h history (slot 15 = h_{-1} must be 0; zero all for safety)
    {
        u32* hz = (u32*)hgs;
        hz[tid] = 0u; hz[512 + tid] = 0u; hz[1024 + tid] = 0u; hz[1536 + tid] = 0u;
    }
    __syncthreads();

    float c_state = 0.f;

    // out matvec for steps [tbase, tbase+8): one (t,o) per thread
    auto out_chunk = [&](int tbase) {
        const int lt = tid >> 6, o = tid & 63;
        const int t = tbase + lt;
        const uint4* hrow = (const uint4*)(hgs + (t & 15) * HID);
        const uint4* wp = (const uint4*)Woutpk;
        float a = bo_reg;
        for (int w4 = 0; w4 < 32; ++w4) {
            uint4 wv = wp[w4 * 64 + o];
            uint4 hv = hrow[w4];
            a = dot2(wv.x, hv.x, a); a = dot2(wv.y, hv.y, a);
            a = dot2(wv.z, hv.z, a); a = dot2(wv.w, hv.w, a);
        }
        outp[(size_t)t * OUT_DIM + o] = a;
        ring[(t % DELAY) * 64 + o] = f16bits(a);
    };

#pragma unroll 1
    for (int ch = 0; ch < NCH; ++ch) {
        // Anti-remat pins each chunk (zero-cost empty asm): canonical homes
        // stay VGPR (wregv) / AGPR (wag) across the whole loop.
#pragma unroll
        for (int q = 0; q < 8; ++q) {
#pragma unroll
            for (int p = 0; p < REGV; ++p)
                asm volatile("" : "+v"(wregv[q][p]));
#pragma unroll
            for (int j = 0; j < AGP; ++j)
                asm volatile("" : "+a"(wag[q][j]));
        }

        const int t0 = ch * CH;
        if (ch > 0) out_chunk(t0 - CH);
        __syncthreads();

        // ---- stage x|fb rows (8 rows x 64 u32) as f16 pairs ----
        {
            int row = tid >> 6, p = tid & 63;
            int t = t0 + row;
            u32 v;
            if (p < 32) {
                float2 x2 = *(const float2*)(xin + (size_t)t * IN_DIM + 2 * p);
                v = pack2(x2.x, x2.y);
            } else {
                int src = t - DELAY;
                if (src >= 0) {
                    int d = 2 * (p - 32);
                    int sl = src % DELAY;
                    v = (u32)ring[sl * 64 + d] | ((u32)ring[sl * 64 + d + 1] << 16);
                } else v = 0u;
            }
            xfst[row * 68 + p] = v;
        }
        __syncthreads();

        // ---- chunk: cb[tl][g'] = bias + x@Wx^T + fb@Wfb^T (dot2, 2 gates/thr)
        {
            float accA[8], accB[8];
#pragma unroll
            for (int i = 0; i < 8; ++i) { accA[i] = 0.f; accB[i] = 0.f; }
            const uint4* bA = Bpk4 + tid;
            const uint4* bB = Bpk4 + 16 * 512 + tid;
#pragma unroll 1
            for (int kb = 0; kb < 16; ++kb) {
                uint4 wA = bA[kb * 512];
                uint4 wB = bB[kb * 512];
#pragma unroll
                for (int tl = 0; tl < 8; ++tl) {
                    uint4 xv = *(const uint4*)(xfst + tl * 68 + kb * 4);
                    accA[tl] = dot2(wA.x, xv.x, accA[tl]);
                    accA[tl] = dot2(wA.y, xv.y, accA[tl]);
                    accA[tl] = dot2(wA.z, xv.z, accA[tl]);
                    accA[tl] = dot2(wA.w, xv.w, accA[tl]);
                    accB[tl] = dot2(wB.x, xv.x, accB[tl]);
                    accB[tl] = dot2(wB.y, xv.y, accB[tl]);
                    accB[tl] = dot2(wB.z, xv.z, accB[tl]);
                    accB[tl] = dot2(wB.w, xv.w, accB[tl]);
                }
            }
            float2 bs = *(const float2*)(bsum_g + 2 * tid);
#pragma unroll
            for (int tl = 0; tl < 8; ++tl)
                cb32[tl * 512 + tid] = pack2(accA[tl] + bs.x, accB[tl] + bs.y);
        }
        __syncthreads();

        // ---- 8 serial steps ----
#pragma unroll 1
        for (int tl = 0; tl < CH; ++tl) {
            const int t = t0 + tl;
            const u32* hrow = (const u32*)hgs + ((t - 1) & 15) * 128 + kq * 32;

            float acc[8];
            if (kq == 0) {
                uint4 cv = *(const uint4*)(cb32 + tl * 512 + gl * 4);
                acc[0] = lo16(cv.x); acc[1] = hi16(cv.x);
                acc[2] = lo16(cv.y); acc[3] = hi16(cv.y);
                acc[4] = lo16(cv.z); acc[5] = hi16(cv.z);
                acc[6] = lo16(cv.w); acc[7] = hi16(cv.w);
            } else {
#pragma unroll
                for (int q = 0; q < 8; ++q) acc[q] = 0.f;
            }
            {   // k-half 0: pairs 0..9 VGPR, 10..15 LDS
                uint4 h0 = *(const uint4*)(hrow + 0);
                uint4 h1 = *(const uint4*)(hrow + 4);
                uint4 h2 = *(const uint4*)(hrow + 8);
                uint4 h3 = *(const uint4*)(hrow + 12);
#pragma unroll
                for (int q = 0; q < 8; ++q) {
                    acc[q] = dot2(wregv[q][0], h0.x, acc[q]);
                    acc[q] = dot2(wregv[q][1], h0.y, acc[q]);
                    acc[q] = dot2(wregv[q][2], h0.z, acc[q]);
                    acc[q] = dot2(wregv[q][3], h0.w, acc[q]);
                    acc[q] = dot2(wregv[q][4], h1.x, acc[q]);
                    acc[q] = dot2(wregv[q][5], h1.y, acc[q]);
                    acc[q] = dot2(wregv[q][6], h1.z, acc[q]);
                    acc[q] = dot2(wregv[q][7], h1.w, acc[q]);
                    acc[q] = dot2(wregv[q][8], h2.x, acc[q]);
                    acc[q] = dot2(wregv[q][9], h2.y, acc[q]);
                    uint4 av = wAl[q * 512 + tid];
                    uint2 bv = wBl[q * 512 + tid];
                    acc[q] = dot2(av.x, h2.z, acc[q]);
                    acc[q] = dot2(av.y, h2.w, acc[q]);
                    acc[q] = dot2(av.z, h3.x, acc[q]);
                    acc[q] = dot2(av.w, h3.y, acc[q]);
                    acc[q] = dot2(bv.x, h3.z, acc[q]);
                    acc[q] = dot2(bv.y, h3.w, acc[q]);
                }
            }
            {   // k-half 1: pair 16 LDS, pairs 17..31 AGPR (v_accvgpr_read)
                uint4 h4 = *(const uint4*)(hrow + 16);
                uint4 h5 = *(const uint4*)(hrow + 20);
                uint4 h6 = *(const uint4*)(hrow + 24);
                uint4 h7 = *(const uint4*)(hrow + 28);
#pragma unroll
                for (int q = 0; q < 8; ++q) {
                    u32 cv = wCl[q * 512 + tid];
                    acc[q] = dot2(cv, h4.x, acc[q]);
                    u32 t0r, t1r, t2r, t3r;
                    AGREAD(t0r, wag[q][0]);  acc[q] = dot2(t0r, h4.y, acc[q]);
                    AGREAD(t1r, wag[q][1]);  acc[q] = dot2(t1r, h4.z, acc[q]);
                    AGREAD(t2r, wag[q][2]);  acc[q] = dot2(t2r, h4.w, acc[q]);
                    AGREAD(t3r, wag[q][3]);  acc[q] = dot2(t3r, h5.x, acc[q]);
                    AGREAD(t0r, wag[q][4]);  acc[q] = dot2(t0r, h5.y, acc[q]);
                    AGREAD(t1r, wag[q][5]);  acc[q] = dot2(t1r, h5.z, acc[q]);
                    AGREAD(t2r, wag[q][6]);  acc[q] = dot2(t2r, h5.w, acc[q]);
                    AGREAD(t3r, wag[q][7]);  acc[q] = dot2(t3r, h6.x, acc[q]);
                    AGREAD(t0r, wag[q][8]);  acc[q] = dot2(t0r, h6.y, acc[q]);
                    AGREAD(t1r, wag[q][9]);  acc[q] = dot2(t1r, h6.z, acc[q]);
                    AGREAD(t2r, wag[q][10]); acc[q] = dot2(t2r, h6.w, acc[q]);
                    AGREAD(t3r, wag[q][11]); acc[q] = dot2(t3r, h7.x, acc[q]);
                    AGREAD(t0r, wag[q][12]); acc[q] = dot2(t0r, h7.y, acc[q]);
                    AGREAD(t1r, wag[q][13]); acc[q] = dot2(t1r, h7.z, acc[q]);
                    AGREAD(t2r, wag[q][14]); acc[q] = dot2(t2r, h7.w, acc[q]);
                }
            }
            {   // one ds_write_b128 of the 8-gate partial (f16)
                uint4 pw;
                pw.x = pack2(acc[0], acc[1]); pw.y = pack2(acc[2], acc[3]);
                pw.z = pack2(acc[4], acc[5]); pw.w = pack2(acc[6], acc[7]);
                *(uint4*)(part + kq * 1024 + gl * 8) = pw;
            }
            __syncthreads();

            if (tid < 256) {
                float s0 = 0.f, s1 = 0.f, s2 = 0.f, s3 = 0.f;
#pragma unroll
                for (int k = 0; k < 4; ++k) {
                    uint2 rd = *(const uint2*)(part + k * 1024 + tid * 4);
                    s0 += lo16(rd.x); s1 += hi16(rd.x);
                    s2 += lo16(rd.y); s3 += hi16(rd.y);
                }
                // permuted order: ty 0=i, 1=f, 2=g, 3=o
                c_state = sigm(s1) * c_state + sigm(s0) * tanh_f(s2);
                float hval = sigm(s3) * tanh_f(c_state);
                hgs[(t & 15) * HID + tid] = f16bits(hval);
            }
            __syncthreads();
        }
    }
    out_chunk(TSTEPS - CH);
}

extern "C" void kernel_launch(void* const* d_in, const int* in_sizes, int n_in,
                              void* d_out, int out_size, void* d_ws, size_t ws_size,
                              hipStream_t stream)
{
    (void)in_sizes; (void)n_in; (void)out_size;
    const float* input = (const float*)d_in[0];
    const float* Wx    = (const float*)d_in[1];
    const float* Wfb   = (const float*)d_in[2];
    const float* Whh   = (const float*)d_in[3];
    const float* bih   = (const float*)d_in[4];
    const float* bhh   = (const float*)d_in[5];
    const float* Wo    = (const float*)d_in[6];
    const float* bog   = (const float*)d_in[7];
    float* out = (float*)d_out;

    if (ws_size < (size_t)WS_NEED) return;

    uint4* Bpk4   = (uint4*)((char*)d_ws + WS_BPK);
    u32*   Woutpk = (u32*)((char*)d_ws + WS_WOUT);
    float* bsum_g = (float*)((char*)d_ws + WS_BSUM);

    prepack<<<dim3(100), dim3(256), 0, stream>>>(
        Wx, Wfb, Whh, Wo, bih, bhh, Bpk4, Woutpk, bsum_g);
    lstm_persist<<<dim3(BATCH), dim3(NTHR), 0, stream>>>(
        input, Whh, bog, Bpk4, Woutpk, bsum_g, out);
}

// Round 6
// 5079.458 us; speedup vs baseline: 1.0226x; 1.0226x over previous
//
#include <hip/hip_runtime.h>

// Delayed-feedback LSTM, persistent kernel: 256 WGs (1/CU), 512 threads.
// LAW (r0-r4): arch VGPRs capped at 128/thread @512thr regardless of
// attributes; AGPRs (v_accvgpr_*) are the extra on-chip storage (r5 proved
// 120 AGPRs/thread live fine; FETCH dropped 2.26->1.60 GB).
// r5 diagnosis: memory is fixed but time is NOT (5.2 ms, VALUBusy 42%) ->
// latency/serialization-bound: 2 barriers/step + LDS partials round-trip +
// 256-thread-only reduce tail idles half the CU every step.
// THIS ROUND: 2-way k-split x 4 gates/thread. Thread 2u+kh owns gates
// (i,f,g,o) of unit u, k-half kh. Cross-thread reduce = ONE packed
// __shfl_xor(,1) (adjacent lane) -> no LDS partials, no reduce phase,
// 1 barrier/step. Both lanes redundantly compute identical c/h (transcend-
// entals spread over all 512 threads). Weight split per gate (64 pairs):
//   pairs  0..17 -> VGPRs  wregv[4][18] = 72 regs
//   pairs 18..47 -> AGPRs  wag[4][30]  = 120 AGPRs (batched reads)
//   pairs 48..63 -> LDS    wl4: 4xuint4/gate, 128 KB, b128 reads
// h-history in LDS (8 KB). Chunk phase (CH=8) and prepack unchanged.

#define BATCH   256
#define TSTEPS  1024
#define IN_DIM  64
#define HID     256
#define OUT_DIM 64
#define DELAY   20
#define CH      8
#define NCH     (TSTEPS / CH)
#define NTHR    512

typedef unsigned int u32;
typedef _Float16 half2_t __attribute__((ext_vector_type(2)));

union H2U { u32 u; half2_t h; };
union H1U { unsigned short s; _Float16 h; };

__device__ __forceinline__ u32 pack2(float a, float b) {
    H2U x; x.h = half2_t{(_Float16)a, (_Float16)b}; return x.u;
}
__device__ __forceinline__ unsigned short f16bits(float a) {
    H1U x; x.h = (_Float16)a; return x.s;
}
__device__ __forceinline__ float lo16(u32 u) {
    H1U x; x.s = (unsigned short)(u & 0xffffu); return (float)x.h;
}
__device__ __forceinline__ float hi16(u32 u) {
    H1U x; x.s = (unsigned short)(u >> 16); return (float)x.h;
}
__device__ __forceinline__ float dot2(u32 w, u32 h, float acc) {
    H2U a; a.u = w; H2U b; b.u = h;
    return __builtin_amdgcn_fdot2(a.h, b.h, acc, false);
}
__device__ __forceinline__ float sigm(float x) {
    float e = __expf(-fabsf(x));
    float p = 1.f / (1.f + e);
    return x >= 0.f ? p : 1.f - p;
}
__device__ __forceinline__ float tanh_f(float x) {
    float e = __expf(-2.f * fabsf(x));
    float r = (1.f - e) / (1.f + e);
    return x >= 0.f ? r : -r;
}

// AGPR access (gfx90a+/gfx950 unified file). AGWRITE/AGREAD volatile so the
// scheduler can neither remat the weights nor hoist 120 reads out of the loop.
#define AGWRITE(dst, src) \
    asm volatile("v_accvgpr_write_b32 %0, %1" : "=a"(dst) : "v"(src))
#define AGREAD(dst, src) \
    asm volatile("v_accvgpr_read_b32 %0, %1" : "=v"(dst) : "a"(src))

// STATIC LDS layout (bytes), total 160384 <= 163840
#define OFF_WL    0        // uint4[16][512]       131072  W_hh pairs 48..63
#define OFF_CB    131072   // u32  [8 tl][512]      16384  chunk pre-acts (2 gates/u32)
#define OFF_RING  147456   // ushort[20][64]         2560  fb ring (f16)
#define OFF_XF    150016   // u32[8][68]             2176  staged x|fb pairs
#define OFF_HG    152192   // ushort[16][256]        8192  h history (f16)
#define SMEM_BYTES 160384

// ws layout (bytes)
#define WS_BPK   0         // 262144: chunk Wx|Wfb packed (uint4)
#define WS_WOUT  262144    // 32768 : packed Wout (u32)
#define WS_BSUM  294912    // 4096  : bias sums (float, permuted)
#define WS_NEED  299008

// permuted gate g' = u*4 + ty  ->  original row ty*256 + u  (ty: 0=i,1=f,2=g,3=o)
__device__ __forceinline__ int orig_row(int gp) {
    return (gp & 3) * 256 + (gp >> 2);
}

__global__ void prepack(const float* __restrict__ Wx,
                        const float* __restrict__ Wfb,
                        const float* __restrict__ Whh,
                        const float* __restrict__ Wout,
                        const float* __restrict__ bih,
                        const float* __restrict__ bhh,
                        uint4* __restrict__ Bpk4,
                        u32* __restrict__ Woutpk,
                        float* __restrict__ bsum_g)
{
    (void)Whh;
    int id = blockIdx.x * 256 + threadIdx.x;
    if (id < 16384) {
        // Bpk4[(j*16+kb)*512 + t]: gate g'=2t+j, K=128 (x|fb), k = kb*8..kb*8+7
        int t = id & 511, rest = id >> 9;
        int kb = rest & 15, j = rest >> 4;
        int r = orig_row(2 * t + j);
        int k0 = kb * 8;
        const float* src = (k0 < 64) ? (Wx + (size_t)r * 64 + k0)
                                     : (Wfb + (size_t)r * 64 + (k0 - 64));
        uint4 v;
        v.x = pack2(src[0], src[1]); v.y = pack2(src[2], src[3]);
        v.z = pack2(src[4], src[5]); v.w = pack2(src[6], src[7]);
        Bpk4[id] = v;
    } else if (id < 16384 + 8192) {
        int s = id - 16384;                 // (w4*64+o)*4+c
        int c = s & 3, o = (s >> 2) & 63, w4 = s >> 8;
        int kp = w4 * 4 + c;
        Woutpk[s] = pack2(Wout[o * HID + 2 * kp], Wout[o * HID + 2 * kp + 1]);
    } else if (id < 16384 + 8192 + 1024) {
        int g = id - 24576;
        int r = orig_row(g);
        bsum_g[g] = bih[r] + bhh[r];
    }
}

__global__ __attribute__((amdgpu_flat_work_group_size(NTHR, NTHR)))
__attribute__((amdgpu_waves_per_eu(2, 2)))
void lstm_persist(const float* __restrict__ input,
                  const float* __restrict__ Whh,
                  const float* __restrict__ bout_g,
                  const uint4* __restrict__ Bpk4,
                  const u32* __restrict__ Woutpk,
                  const float* __restrict__ bsum_g,
                  float* __restrict__ out)
{
    __shared__ alignas(16) unsigned char smem[SMEM_BYTES];
    uint4*          wl4   = (uint4*)(smem + OFF_WL);
    u32*            cb32  = (u32*)(smem + OFF_CB);
    unsigned short* ring  = (unsigned short*)(smem + OFF_RING);
    u32*            xfst  = (u32*)(smem + OFF_XF);
    unsigned short* hgs   = (unsigned short*)(smem + OFF_HG);

    const int tid = threadIdx.x;
    const int b   = blockIdx.x;
    const int u   = tid >> 1;         // unit 0..255
    const int kh  = tid & 1;          // k-half (0: k 0..127, 1: k 128..255)

    const float* xin  = input + (size_t)b * TSTEPS * IN_DIM;
    float*       outp = out + (size_t)b * TSTEPS * OUT_DIM;
    const float bo_reg = bout_g[tid & 63];

    // ---- init: W_hh rows (i,f,g,o of unit u), k-half kh ----
    // per gate (64 pairs): 0..17 VGPR, 18..47 AGPR, 48..63 LDS
    u32 wregv[4][18];
    u32 wag[4][30];
#pragma unroll
    for (int j = 0; j < 4; ++j) {
        const int r = j * 256 + u;              // orig_row(u*4 + j)
        const float* wrow = Whh + (size_t)r * HID + kh * 128;
#pragma unroll
        for (int p = 0; p < 18; ++p) {
            float2 w2 = *(const float2*)(wrow + 2 * p);
            wregv[j][p] = pack2(w2.x, w2.y);
        }
#pragma unroll
        for (int p = 0; p < 30; ++p) {
            float2 w2 = *(const float2*)(wrow + 36 + 2 * p);
            u32 v = pack2(w2.x, w2.y);
            AGWRITE(wag[j][p], v);
        }
#pragma unroll
        for (int pp = 0; pp < 4; ++pp) {
            const float* w = wrow + 96 + 8 * pp;
            uint4 v;
            v.x = pack2(w[0], w[1]); v.y = pack2(w[2], w[3]);
            v.z = pack2(w[4], w[5]); v.w = pack2(w[6], w[7]);
            wl4[(j * 4 + pp) * 512 + tid] = v;
        }
    }
    // zero h history (slot 15 = h_{-1} must be 0; zero all for safety)
    {
        u32* hz = (u32*)hgs;
        hz[tid] = 0u; hz[512 + tid] = 0u; hz[1024 + tid] = 0u; hz[1536 + tid] = 0u;
    }
    __syncthreads();

    float c_state = 0.f;

    // out matvec for steps [tbase, tbase+8): one (t,o) per thread
    auto out_chunk = [&](int tbase) {
        const int lt = tid >> 6, o = tid & 63;
        const int t = tbase + lt;
        const uint4* hrow = (const uint4*)(hgs + (t & 15) * HID);
        const uint4* wp = (const uint4*)Woutpk;
        float a = bo_reg;
        for (int w4 = 0; w4 < 32; ++w4) {
            uint4 wv = wp[w4 * 64 + o];
            uint4 hv = hrow[w4];
            a = dot2(wv.x, hv.x, a); a = dot2(wv.y, hv.y, a);
            a = dot2(wv.z, hv.z, a); a = dot2(wv.w, hv.w, a);
        }
        outp[(size_t)t * OUT_DIM + o] = a;
        ring[(t % DELAY) * 64 + o] = f16bits(a);
    };

#pragma unroll 1
    for (int ch = 0; ch < NCH; ++ch) {
        // Anti-remat pins each chunk (zero-cost empty asm).
#pragma unroll
        for (int j = 0; j < 4; ++j) {
#pragma unroll
            for (int p = 0; p < 18; ++p)
                asm volatile("" : "+v"(wregv[j][p]));
#pragma unroll
            for (int p = 0; p < 30; ++p)
                asm volatile("" : "+a"(wag[j][p]));
        }

        const int t0 = ch * CH;
        if (ch > 0) out_chunk(t0 - CH);
        __syncthreads();

        // ---- stage x|fb rows (8 rows x 64 u32) as f16 pairs ----
        {
            int row = tid >> 6, p = tid & 63;
            int t = t0 + row;
            u32 v;
            if (p < 32) {
                float2 x2 = *(const float2*)(xin + (size_t)t * IN_DIM + 2 * p);
                v = pack2(x2.x, x2.y);
            } else {
                int src = t - DELAY;
                if (src >= 0) {
                    int d = 2 * (p - 32);
                    int sl = src % DELAY;
                    v = (u32)ring[sl * 64 + d] | ((u32)ring[sl * 64 + d + 1] << 16);
                } else v = 0u;
            }
            xfst[row * 68 + p] = v;
        }
        __syncthreads();

        // ---- chunk: cb[tl][g'] = bias + x@Wx^T + fb@Wfb^T (dot2, 2 gates/thr)
        {
            float accA[8], accB[8];
#pragma unroll
            for (int i = 0; i < 8; ++i) { accA[i] = 0.f; accB[i] = 0.f; }
            const uint4* bA = Bpk4 + tid;
            const uint4* bB = Bpk4 + 16 * 512 + tid;
#pragma unroll 1
            for (int kb = 0; kb < 16; ++kb) {
                uint4 wA = bA[kb * 512];
                uint4 wB = bB[kb * 512];
#pragma unroll
                for (int tl = 0; tl < 8; ++tl) {
                    uint4 xv = *(const uint4*)(xfst + tl * 68 + kb * 4);
                    accA[tl] = dot2(wA.x, xv.x, accA[tl]);
                    accA[tl] = dot2(wA.y, xv.y, accA[tl]);
                    accA[tl] = dot2(wA.z, xv.z, accA[tl]);
                    accA[tl] = dot2(wA.w, xv.w, accA[tl]);
                    accB[tl] = dot2(wB.x, xv.x, accB[tl]);
                    accB[tl] = dot2(wB.y, xv.y, accB[tl]);
                    accB[tl] = dot2(wB.z, xv.z, accB[tl]);
                    accB[tl] = dot2(wB.w, xv.w, accB[tl]);
                }
            }
            float2 bs = *(const float2*)(bsum_g + 2 * tid);
#pragma unroll
            for (int tl = 0; tl < 8; ++tl)
                cb32[tl * 512 + tid] = pack2(accA[tl] + bs.x, accB[tl] + bs.y);
        }
        __syncthreads();

        // ---- 8 serial steps: 1 barrier each, shuffle-reduce, no partials ----
#pragma unroll 1
        for (int tl = 0; tl < CH; ++tl) {
            const int t = t0 + tl;
            const u32* hrow = (const u32*)hgs + ((t - 1) & 15) * 128 + kh * 64;

            float acc[4], ac2[4];
            if (kh == 0) {
                uint2 cv = *(const uint2*)(cb32 + tl * 512 + 2 * u);
                acc[0] = lo16(cv.x); acc[1] = hi16(cv.x);
                acc[2] = lo16(cv.y); acc[3] = hi16(cv.y);
            } else {
#pragma unroll
                for (int j = 0; j < 4; ++j) acc[j] = 0.f;
            }
#pragma unroll
            for (int j = 0; j < 4; ++j) ac2[j] = 0.f;

            {   // batch 0: h pairs 0..15, VGPR weights 0..15
                uint4 h0 = *(const uint4*)(hrow + 0);
                uint4 h1 = *(const uint4*)(hrow + 4);
                uint4 h2 = *(const uint4*)(hrow + 8);
                uint4 h3 = *(const uint4*)(hrow + 12);
#pragma unroll
                for (int j = 0; j < 4; ++j) {
                    acc[j] = dot2(wregv[j][0], h0.x, acc[j]);
                    ac2[j] = dot2(wregv[j][1], h0.y, ac2[j]);
                    acc[j] = dot2(wregv[j][2], h0.z, acc[j]);
                    ac2[j] = dot2(wregv[j][3], h0.w, ac2[j]);
                    acc[j] = dot2(wregv[j][4], h1.x, acc[j]);
                    ac2[j] = dot2(wregv[j][5], h1.y, ac2[j]);
                    acc[j] = dot2(wregv[j][6], h1.z, acc[j]);
                    ac2[j] = dot2(wregv[j][7], h1.w, ac2[j]);
                    acc[j] = dot2(wregv[j][8], h2.x, acc[j]);
                    ac2[j] = dot2(wregv[j][9], h2.y, ac2[j]);
                    acc[j] = dot2(wregv[j][10], h2.z, acc[j]);
                    ac2[j] = dot2(wregv[j][11], h2.w, ac2[j]);
                    acc[j] = dot2(wregv[j][12], h3.x, acc[j]);
                    ac2[j] = dot2(wregv[j][13], h3.y, ac2[j]);
                    acc[j] = dot2(wregv[j][14], h3.z, acc[j]);
                    ac2[j] = dot2(wregv[j][15], h3.w, ac2[j]);
                }
            }
            {   // batch 1: h pairs 16..31, VGPR 16..17 + AGPR 0..13 (batched)
                uint4 h4 = *(const uint4*)(hrow + 16);
                uint4 h5 = *(const uint4*)(hrow + 20);
                uint4 h6 = *(const uint4*)(hrow + 24);
                uint4 h7 = *(const uint4*)(hrow + 28);
#pragma unroll
                for (int j = 0; j < 4; ++j) {
                    acc[j] = dot2(wregv[j][16], h4.x, acc[j]);
                    ac2[j] = dot2(wregv[j][17], h4.y, ac2[j]);
                    u32 w0, w1, w2, w3;
                    AGREAD(w0, wag[j][0]); AGREAD(w1, wag[j][1]);
                    AGREAD(w2, wag[j][2]); AGREAD(w3, wag[j][3]);
                    acc[j] = dot2(w0, h4.z, acc[j]);
                    ac2[j] = dot2(w1, h4.w, ac2[j]);
                    acc[j] = dot2(w2, h5.x, acc[j]);
                    ac2[j] = dot2(w3, h5.y, ac2[j]);
                    AGREAD(w0, wag[j][4]); AGREAD(w1, wag[j][5]);
                    AGREAD(w2, wag[j][6]); AGREAD(w3, wag[j][7]);
                    acc[j] = dot2(w0, h5.z, acc[j]);
                    ac2[j] = dot2(w1, h5.w, ac2[j]);
                    acc[j] = dot2(w2, h6.x, acc[j]);
                    ac2[j] = dot2(w3, h6.y, ac2[j]);
                    AGREAD(w0, wag[j][8]); AGREAD(w1, wag[j][9]);
                    AGREAD(w2, wag[j][10]); AGREAD(w3, wag[j][11]);
                    acc[j] = dot2(w0, h6.z, acc[j]);
                    ac2[j] = dot2(w1, h6.w, ac2[j]);
                    acc[j] = dot2(w2, h7.x, acc[j]);
                    ac2[j] = dot2(w3, h7.y, ac2[j]);
                    AGREAD(w0, wag[j][12]); AGREAD(w1, wag[j][13]);
                    acc[j] = dot2(w0, h7.z, acc[j]);
                    ac2[j] = dot2(w1, h7.w, ac2[j]);
                }
            }
            {   // batch 2: h pairs 32..47, AGPR 14..29 (batched)
                uint4 h8 = *(const uint4*)(hrow + 32);
                uint4 h9 = *(const uint4*)(hrow + 36);
                uint4 ha = *(const uint4*)(hrow + 40);
                uint4 hb = *(const uint4*)(hrow + 44);
#pragma unroll
                for (int j = 0; j < 4; ++j) {
                    u32 w0, w1, w2, w3;
                    AGREAD(w0, wag[j][14]); AGREAD(w1, wag[j][15]);
                    AGREAD(w2, wag[j][16]); AGREAD(w3, wag[j][17]);
                    acc[j] = dot2(w0, h8.x, acc[j]);
                    ac2[j] = dot2(w1, h8.y, ac2[j]);
                    acc[j] = dot2(w2, h8.z, acc[j]);
                    ac2[j] = dot2(w3, h8.w, ac2[j]);
                    AGREAD(w0, wag[j][18]); AGREAD(w1, wag[j][19]);
                    AGREAD(w2, wag[j][20]); AGREAD(w3, wag[j][21]);
                    acc[j] = dot2(w0, h9.x, acc[j]);
                    ac2[j] = dot2(w1, h9.y, ac2[j]);
                    acc[j] = dot2(w2, h9.z, acc[j]);
                    ac2[j] = dot2(w3, h9.w, ac2[j]);
                    AGREAD(w0, wag[j][22]); AGREAD(w1, wag[j][23]);
                    AGREAD(w2, wag[j][24]); AGREAD(w3, wag[j][25]);
                    acc[j] = dot2(w0, ha.x, acc[j]);
                    ac2[j] = dot2(w1, ha.y, ac2[j]);
                    acc[j] = dot2(w2, ha.z, acc[j]);
                    ac2[j] = dot2(w3, ha.w, ac2[j]);
                    AGREAD(w0, wag[j][26]); AGREAD(w1, wag[j][27]);
                    AGREAD(w2, wag[j][28]); AGREAD(w3, wag[j][29]);
                    acc[j] = dot2(w0, hb.x, acc[j]);
                    ac2[j] = dot2(w1, hb.y, ac2[j]);
                    acc[j] = dot2(w2, hb.z, acc[j]);
                    ac2[j] = dot2(w3, hb.w, ac2[j]);
                }
            }
            {   // batch 3: h pairs 48..63, LDS weights (4x b128 per gate)
                uint4 hc = *(const uint4*)(hrow + 48);
                uint4 hd = *(const uint4*)(hrow + 52);
                uint4 he = *(const uint4*)(hrow + 56);
                uint4 hf = *(const uint4*)(hrow + 60);
#pragma unroll
                for (int j = 0; j < 4; ++j) {
                    uint4 v0 = wl4[(j * 4 + 0) * 512 + tid];
                    uint4 v1 = wl4[(j * 4 + 1) * 512 + tid];
                    uint4 v2 = wl4[(j * 4 + 2) * 512 + tid];
                    uint4 v3 = wl4[(j * 4 + 3) * 512 + tid];
                    acc[j] = dot2(v0.x, hc.x, acc[j]);
                    ac2[j] = dot2(v0.y, hc.y, ac2[j]);
                    acc[j] = dot2(v0.z, hc.z, acc[j]);
                    ac2[j] = dot2(v0.w, hc.w, ac2[j]);
                    acc[j] = dot2(v1.x, hd.x, acc[j]);
                    ac2[j] = dot2(v1.y, hd.y, ac2[j]);
                    acc[j] = dot2(v1.z, hd.z, acc[j]);
                    ac2[j] = dot2(v1.w, hd.w, ac2[j]);
                    acc[j] = dot2(v2.x, he.x, acc[j]);
                    ac2[j] = dot2(v2.y, he.y, ac2[j]);
                    acc[j] = dot2(v2.z, he.z, acc[j]);
                    ac2[j] = dot2(v2.w, he.w, ac2[j]);
                    acc[j] = dot2(v3.x, hf.x, acc[j]);
                    ac2[j] = dot2(v3.y, hf.y, ac2[j]);
                    acc[j] = dot2(v3.z, hf.z, acc[j]);
                    ac2[j] = dot2(v3.w, hf.w, ac2[j]);
                }
            }

            // ---- pair-exchange reduce (adjacent lane holds other k-half) ----
            {
                u32 pa = pack2(acc[0] + ac2[0], acc[1] + ac2[1]);
                u32 pb = pack2(acc[2] + ac2[2], acc[3] + ac2[3]);
                u32 qa = (u32)__shfl_xor((int)pa, 1, 64);
                u32 qb = (u32)__shfl_xor((int)pb, 1, 64);
                float Si = lo16(pa) + lo16(qa);
                float Sf = hi16(pa) + hi16(qa);
                float Sg = lo16(pb) + lo16(qb);
                float So = hi16(pb) + hi16(qb);
                // both lanes compute identical c/h (deterministic)
                c_state = sigm(Sf) * c_state + sigm(Si) * tanh_f(Sg);
                float hval = sigm(So) * tanh_f(c_state);
                if (kh == 0)
                    hgs[(t & 15) * HID + u] = f16bits(hval);
            }
            __syncthreads();
        }
    }
    out_chunk(TSTEPS - CH);
}

extern "C" void kernel_launch(void* const* d_in, const int* in_sizes, int n_in,
                              void* d_out, int out_size, void* d_ws, size_t ws_size,
                              hipStream_t stream)
{
    (void)in_sizes; (void)n_in; (void)out_size;
    const float* input = (const float*)d_in[0];
    const float* Wx    = (const float*)d_in[1];
    const float* Wfb   = (const float*)d_in[2];
    const float* Whh   = (const float*)d_in[3];
    const float* bih   = (const float*)d_in[4];
    const float* bhh   = (const float*)d_in[5];
    const float* Wo    = (const float*)d_in[6];
    const float* bog   = (const float*)d_in[7];
    float* out = (float*)d_out;

    if (ws_size < (size_t)WS_NEED) return;

    uint4* Bpk4   = (uint4*)((char*)d_ws + WS_BPK);
    u32*   Woutpk = (u32*)((char*)d_ws + WS_WOUT);
    float* bsum_g = (float*)((char*)d_ws + WS_BSUM);

    prepack<<<dim3(100), dim3(256), 0, stream>>>(
        Wx, Wfb, Whh, Wo, bih, bhh, Bpk4, Woutpk, bsum_g);
    lstm_persist<<<dim3(BATCH), dim3(NTHR), 0, stream>>>(
        input, Whh, bog, Bpk4, Woutpk, bsum_g, out);
}